// Round 5
// baseline (326.197 us; speedup 1.0000x reference)
//
#include <hip/hip_runtime.h>
#include <math.h>

#define SMK    2048
#define TAPS   32
#define OUTLEN (SMK + TAPS - 1)   // 2079
#define PAD    32
#define SLOTS  (PAD + SMK + PAD)  // 2112 float2
#define NF4    (SLOTS / 2)        // 1056 float4 slots
#define MDFT   64
#define ROWS_PER_BLOCK 8
#define NBLOCKS 2048

// Involution swizzle at float4-slot granularity: bits[2:0] ^= bits[5:3].
// Write side (lane-consecutive slots) and read side (stride-4 slots) both
// land at 2-way bank aliasing = free.
__device__ __forceinline__ int swz4(int s) { return s ^ ((s >> 3) & 7); }

__device__ __forceinline__ float rfl(float x) {
    return __int_as_float(__builtin_amdgcn_readfirstlane(__float_as_int(x)));
}

__global__ __launch_bounds__(256, 4)
void conv_kernel(const float* __restrict__ input,
                 const float* __restrict__ cof,
                 float* __restrict__ out0,
                 float* __restrict__ out1)
{
    __shared__ float4 s4[NF4];
    __shared__ float2 s_tw[MDFT];

    const int tid = threadIdx.x;

    // One-time: zero pads (slots [0,16) and [1040,1056)) + DFT twiddles.
    if (tid < 16) {
        s4[swz4(tid)] = make_float4(0.f, 0.f, 0.f, 0.f);
    } else if (tid < 32) {
        s4[swz4(1024 + tid)] = make_float4(0.f, 0.f, 0.f, 0.f);  // 1040..1055
    }
    if (tid >= 64 && tid < 128) {
        int j = tid - 64;
        float sv, cv;
        __sincosf(-2.0f * (float)M_PI * (float)j / (float)MDFT, &sv, &cv);
        s_tw[j] = make_float2(cv, sv);
    }

    // Prologue: issue row-0 staging loads.
    float4 stg[4];
    {
        const float4* g = (const float4*)(input + (size_t)blockIdx.x * (SMK * 2));
        #pragma unroll
        for (int k2 = 0; k2 < 4; ++k2) stg[k2] = g[tid + 256 * k2];
    }

    #pragma unroll 1
    for (int it = 0; it < ROWS_PER_BLOCK; ++it) {
        const int r = blockIdx.x + NBLOCKS * it;

        // Taps -> SGPR (uniform scalar loads; latency hidden by barriers).
        const float2* __restrict__ ct = (const float2*)(cof + (size_t)r * (TAPS * 2));
        float hre[TAPS], him[TAPS];
        #pragma unroll
        for (int l = 0; l < TAPS; ++l) {
            float2 tv = ct[l];
            hre[l] = rfl(tv.x);
            him[l] = rfl(tv.y);
        }

        __syncthreads();   // prior row's LDS reads done; prefetch loads drained
        #pragma unroll
        for (int k2 = 0; k2 < 4; ++k2)
            s4[swz4(16 + tid + 256 * k2)] = stg[k2];
        __syncthreads();   // row r visible in LDS

        // Issue next row's loads NOW (after the barrier): they stay in
        // flight under the entire compute phase of row r.
        if (it + 1 < ROWS_PER_BLOCK) {
            const float4* g = (const float4*)(input + (size_t)(r + NBLOCKS) * (SMK * 2));
            #pragma unroll
            for (int k2 = 0; k2 < 4; ++k2) stg[k2] = g[tid + 256 * k2];
        }

        float2* go2 = (float2*)(out0 + (size_t)r * OUTLEN * 2);

        // ---- main: 8 consecutive outputs per thread, 2 tap chunks of 16 ----
        float2 acc[8];
        #pragma unroll
        for (int k = 0; k < 8; ++k) acc[k] = make_float2(0.f, 0.f);

        #pragma unroll
        for (int c = 0; c < 2; ++c) {
            // chunk c: taps l = 16c..16c+15; window = 12 float4 from swizzled slots
            float4 w[12];
            #pragma unroll
            for (int i = 0; i < 12; ++i)
                w[i] = s4[swz4(4 * tid + 8 - 8 * c + i)];

            #pragma unroll
            for (int lp = 0; lp < 16; ++lp) {
                const float hr = hre[16 * c + lp];
                const float hi = him[16 * c + lp];
                #pragma unroll
                for (int k = 0; k < 8; ++k) {
                    const int q = 16 + k - lp;          // 1..23, compile-time
                    const float sx = (q & 1) ? w[q >> 1].z : w[q >> 1].x;
                    const float sy = (q & 1) ? w[q >> 1].w : w[q >> 1].y;
                    acc[k].x = fmaf(sx, hr, fmaf(-sy, hi, acc[k].x));
                    acc[k].y = fmaf(sx, hi, fmaf( sy, hr, acc[k].y));
                }
            }
            // keep chunk-1's window from being hoisted (caps VGPR pressure)
            __builtin_amdgcn_sched_barrier(0);
        }

        const int t0 = 8 * tid;
        #pragma unroll
        for (int k = 0; k < 8; ++k) go2[t0 + k] = acc[k];

        // ---- wave 1: fused 64-pt DFT of zero-padded taps ----
        if (tid >= 64 && tid < 128) {
            const int kk = tid - 64;
            float ax = 0.f, ay = 0.f;
            #pragma unroll
            for (int l = 0; l < TAPS; ++l) {
                float2 w = s_tw[(kk * l) & (MDFT - 1)];
                ax = fmaf(w.x, hre[l], fmaf(-w.y, him[l], ax));
                ay = fmaf(w.y, hre[l], fmaf( w.x, him[l], ay));
            }
            ((float2*)out1)[(size_t)r * MDFT + kk] = make_float2(ax, ay);
        }
        // ---- wave 2: tail outputs t = 2048..2078 ----
        else if (tid >= 128 && tid < 128 + (OUTLEN - SMK)) {
            const int t = SMK + (tid - 128);
            float ax = 0.f, ay = 0.f;
            #pragma unroll
            for (int l = 0; l < TAPS; ++l) {
                const int P = PAD + t - l;              // back pad supplies zeros
                float4 v = s4[swz4(P >> 1)];
                const float sx = (P & 1) ? v.z : v.x;
                const float sy = (P & 1) ? v.w : v.y;
                ax = fmaf(sx, hre[l], fmaf(-sy, him[l], ax));
                ay = fmaf(sx, him[l], fmaf( sy, hre[l], ay));
            }
            go2[t] = make_float2(ax, ay);
        }
    }
}

extern "C" void kernel_launch(void* const* d_in, const int* in_sizes, int n_in,
                              void* d_out, int out_size, void* d_ws, size_t ws_size,
                              hipStream_t stream)
{
    const float* input = (const float*)d_in[0];  // (N,P,2048,2) fp32
    const float* cof   = (const float*)d_in[1];  // (N,P,32,2)   fp32
    // d_in[2] is M (=64), compile-time here.

    float* out0 = (float*)d_out;                                   // (NP, 2079, 2)
    const int NP = in_sizes[0] / (SMK * 2);                        // 16384
    float* out1 = out0 + (size_t)NP * OUTLEN * 2;                  // (NP, 64, 2)

    conv_kernel<<<NBLOCKS, 256, 0, stream>>>(input, cof, out0, out1);
}

// Round 6
// 146.372 us; speedup vs baseline: 2.2285x; 2.2285x over previous
//
#include <hip/hip_runtime.h>
#include <math.h>

#define SMK    2048
#define TAPS   32
#define OUTLEN (SMK + TAPS - 1)   // 2079
#define PAD    32
#define SLOTS  (PAD + SMK + PAD)  // 2112 float2 slots
#define MDFT   64

typedef float v2f __attribute__((ext_vector_type(2)));

// Bijective 8B-slot swizzle (round-2 proven conflict-free for the
// 64B-lane-stride window reads).
__device__ __forceinline__ int swz(int p) { return p ^ ((p >> 4) & 15); }

__device__ __forceinline__ float rfl(float x) {
    return __int_as_float(__builtin_amdgcn_readfirstlane(__float_as_int(x)));
}

__global__ __launch_bounds__(256)
__attribute__((amdgpu_waves_per_eu(4, 4)))   // pin 4 waves/EU -> 128-VGPR budget
void conv_kernel(const float* __restrict__ input,
                 const float* __restrict__ cof,
                 float* __restrict__ out0,
                 float* __restrict__ out1)
{
    __shared__ float2 s_sig[SLOTS];
    __shared__ float2 s_tw[MDFT];

    const int tid = threadIdx.x;
    const int row = blockIdx.x;

    // ---- stage signal row (16 KB) into swizzled LDS ----
    const float4* gin = (const float4*)(input + (size_t)row * (SMK * 2));
    #pragma unroll
    for (int k = 0; k < 4; ++k) {
        float4 v = gin[tid + 256 * k];
        int i0 = PAD + 2 * (tid + 256 * k);
        s_sig[swz(i0)]     = make_float2(v.x, v.y);
        s_sig[swz(i0 + 1)] = make_float2(v.z, v.w);
    }
    if (tid < PAD) {
        s_sig[swz(tid)] = make_float2(0.f, 0.f);            // front pad
    } else if (tid < 2 * PAD) {
        s_sig[swz(SMK + tid)] = make_float2(0.f, 0.f);      // back pad 2080..2111
    }
    if (tid >= 64 && tid < 128) {                           // twiddles e^{-2pi i j/64}
        int j = tid - 64;
        float sv, cv;
        __sincosf(-2.0f * (float)M_PI * (float)j / (float)MDFT, &sv, &cv);
        s_tw[j] = make_float2(cv, sv);
    }

    // ---- taps -> SGPR (block-uniform via readfirstlane) ----
    const float2* __restrict__ ct = (const float2*)(cof + (size_t)row * (TAPS * 2));
    float hre[TAPS], him[TAPS];
    #pragma unroll
    for (int l = 0; l < TAPS; ++l) {
        float2 tv = ct[l];
        hre[l] = rfl(tv.x);
        him[l] = rfl(tv.y);
    }
    __syncthreads();

    // ---- each thread: 8 consecutive outputs t0..t0+7, register window ----
    const int t0 = tid * 8;

    float2 win[39];                     // sig[t0-31 .. t0+7]
    #pragma unroll
    for (int m = 0; m < 39; ++m) win[m] = s_sig[swz(t0 + 1 + m)];

    // Packed-FMA pairing: accA += (s.x,s.x)*(hr,hi); accB += (s.y,s.y)*(hr,hi)
    // Final: re = A.x - B.y ; im = A.y + B.x   (2 pk_fma per tap/output)
    v2f accA[8], accB[8];
    #pragma unroll
    for (int k = 0; k < 8; ++k) { accA[k] = (v2f)(0.f); accB[k] = (v2f)(0.f); }

    #pragma unroll
    for (int l = 0; l < TAPS; ++l) {
        const v2f hv = { hre[l], him[l] };     // SGPR pair, uniform
        #pragma unroll
        for (int k = 0; k < 8; ++k) {
            const float2 s = win[k + 31 - l];  // sig[t0+k-l]
            accA[k] = __builtin_elementwise_fma((v2f){ s.x, s.x }, hv, accA[k]);
            accB[k] = __builtin_elementwise_fma((v2f){ s.y, s.y }, hv, accB[k]);
        }
    }

    float2* go2 = (float2*)(out0 + (size_t)row * (OUTLEN * 2));
    #pragma unroll
    for (int k = 0; k < 8; ++k)
        go2[t0 + k] = make_float2(accA[k].x - accB[k].y, accA[k].y + accB[k].x);

    // ---- wave 0 extra: fused 64-pt DFT of zero-padded taps ----
    if (tid < MDFT) {
        const int kk = tid;
        v2f aA = (v2f)(0.f), aB = (v2f)(0.f);
        #pragma unroll
        for (int l = 0; l < TAPS; ++l) {
            const v2f hv = { hre[l], him[l] };
            float2 w = s_tw[(kk * l) & (MDFT - 1)];
            aA = __builtin_elementwise_fma((v2f){ w.x, w.x }, hv, aA);
            aB = __builtin_elementwise_fma((v2f){ w.y, w.y }, hv, aB);
        }
        // (hr+i hi)(wx+i wy): re = hr*wx - hi*wy = A.x - B.y ; im = hr*wy + hi*wx = B.x + A.y
        ((float2*)out1)[(size_t)row * MDFT + kk] =
            make_float2(aA.x - aB.y, aA.y + aB.x);
    }
    // ---- wave 2 extra: tail outputs t = 2048..2078 ----
    else if (tid >= 128 && tid < 128 + (OUTLEN - SMK)) {
        const int t = SMK + (tid - 128);
        v2f aA = (v2f)(0.f), aB = (v2f)(0.f);
        #pragma unroll
        for (int l = 0; l < TAPS; ++l) {
            const v2f hv = { hre[l], him[l] };
            float2 s = s_sig[swz(PAD + t - l)];   // back pad supplies zeros
            aA = __builtin_elementwise_fma((v2f){ s.x, s.x }, hv, aA);
            aB = __builtin_elementwise_fma((v2f){ s.y, s.y }, hv, aB);
        }
        go2[t] = make_float2(aA.x - aB.y, aA.y + aB.x);
    }
}

extern "C" void kernel_launch(void* const* d_in, const int* in_sizes, int n_in,
                              void* d_out, int out_size, void* d_ws, size_t ws_size,
                              hipStream_t stream)
{
    const float* input = (const float*)d_in[0];  // (N,P,2048,2) fp32
    const float* cof   = (const float*)d_in[1];  // (N,P,32,2)   fp32
    // d_in[2] is M (=64), compile-time here.

    const int NP = in_sizes[0] / (SMK * 2);      // 16384

    float* out0 = (float*)d_out;                           // (NP, 2079, 2)
    float* out1 = out0 + (size_t)NP * OUTLEN * 2;          // (NP, 64, 2)

    conv_kernel<<<NP, 256, 0, stream>>>(input, cof, out0, out1);
}